// Round 12
// baseline (114.431 us; speedup 1.0000x reference)
//
#include <hip/hip_runtime.h>
#include <hip/hip_fp16.h>
#include <math.h>

#define N_IN   512
#define N_OUT  256
#define NCOEF  257
#define BATCH  1024
#define LN_EPS 1e-5f
#define G0F (-1.0f - 3.0f * (2.0f / 254.0f))

#define ROWQ 20                 // dwords per q-row: 16 data + 4 pad (bank rotate)
#define NQ   129
#define SLABW (NQ * ROWQ)       // 2580 dwords

// physical dword of logical (q-row, o-col oo in [0,16)): quad-preserving XOR
#define SLOT(q_, oo_) ((q_) * ROWQ + (((((oo_) >> 2) ^ ((q_) & 3))) << 2) + ((oo_) & 3))

// DPP quad_perm broadcast: all 4 lanes of a quad read lane (ctrl-selected)
#define QP(v_, C_) ((unsigned)__builtin_amdgcn_mov_dpp((int)(v_), (C_), 0xf, 0xf, true))

static __device__ __forceinline__ unsigned pk_bf16x2(float a, float b) {
    unsigned ua = ((__float_as_uint(a) + 0x8000u) >> 16) & 0xffffu;
    unsigned ub = (__float_as_uint(b) + 0x8000u) & 0xffff0000u;
    return ua | ub;
}

static __device__ __forceinline__ float dot2bf(unsigned w, unsigned s, float c) {
    float d;
    asm("v_dot2_f32_bf16 %0, %1, %2, %3" : "=v"(d) : "v"(w), "v"(s), "v"(c));
    return d;
}

// 6-wide even-aligned spline window: w'[j] for g = pe+j, pe = clamp(pb)&~1.
// uint4: x=(w'0,w'1) y=(w'2,w'3) z=(w'4,w'5) bf16-pairs; w = pe | f16(tanh)<<16
static __device__ __forceinline__ uint4 spline_pack(float xv) {
    const float e2 = __expf(2.f * xv);
    const float tx = 1.f - 2.f / (e2 + 1.f);        // tanh(xv)
    const float u  = (xv - G0F) * 127.f;
    const bool has = (u >= 0.f) && (u < 260.f);
    const float uf = has ? u : 0.f;
    int m = (int)uf;
    if (m > 259) m = 259;
    const float tt = uf - (float)m;
    const float t2 = tt * tt, t3 = t2 * tt;
    const float omt = 1.f - tt;
    float a0 = omt * omt * omt * (1.f / 6.f);
    float a1 = (3.f * t3 - 6.f * t2 + 4.f) * (1.f / 6.f);
    float a2 = (-3.f * t3 + 3.f * t2 + 3.f * tt + 1.f) * (1.f / 6.f);
    float a3 = t3 * (1.f / 6.f);
    if (!has) { a0 = a1 = a2 = a3 = 0.f; }
    const int pb  = m - 3;
    const int pbc = pb < 0 ? 0 : (pb > 253 ? 253 : pb);
    const int d   = pbc - pb;                       // [-3,3]
    if (d >= 1)  { a0 = a1; a1 = a2; a2 = a3; a3 = 0.f; }
    if (d >= 2)  { a0 = a1; a1 = a2; a2 = a3; a3 = 0.f; }
    if (d >= 3)  { a0 = a1; a1 = a2; a2 = a3; a3 = 0.f; }
    if (d <= -1) { a3 = a2; a2 = a1; a1 = a0; a0 = 0.f; }
    if (d <= -2) { a3 = a2; a2 = a1; a1 = a0; a0 = 0.f; }
    if (d <= -3) { a3 = a2; a2 = a1; a1 = a0; a0 = 0.f; }
    uint4 r;
    if (pbc & 1) {        // window (0,a0,a1,a2,a3,0)
        r.x = pk_bf16x2(0.f, a0);
        r.y = pk_bf16x2(a1, a2);
        r.z = pk_bf16x2(a3, 0.f);
    } else {              // window (a0,a1,a2,a3,0,0)
        r.x = pk_bf16x2(a0, a1);
        r.y = pk_bf16x2(a2, a3);
        r.z = 0u;
    }
    r.w = (unsigned)(pbc & ~1) |
          ((unsigned)__half_as_ushort(__float2half(tx)) << 16);
    return r;
}

__global__ __launch_bounds__(1024, 4) void kan_main(
    const float* __restrict__ x, const float* __restrict__ W,
    const float* __restrict__ sw, float* __restrict__ part)
{
    const int bid = blockIdx.x;
    const int bc = bid & 1;             // fastest: 2 sw-slab sharers, LLC-hot
    const int oc = (bid >> 1) & 15;
    const int ig = bid >> 5;            // [0,16)
    const int o0 = oc * 16, i0 = ig * 32, b0 = bc * 512;
    const int t = threadIdx.x;

    __shared__ __align__(16) unsigned slab[2][2][SLABW];   // 41.3 KB (dbuf)
    __shared__ __align__(16) float Wl[2][2][16];

    // compute mapping: quad=(wv,bl); b_own(bp) = b0 + wv*32 + bp*16 + bl
    const int wv = t >> 6, bl = (t >> 2) & 15, og = t & 3;
    // staging mapping: o-row soo, float4-chunk sgc
    const int soo = t & 15;             // [0,16)
    const int sgc = t >> 4;             // [0,64)

    const float* swrow = sw + ((size_t)(o0 + soo) * N_IN + i0) * NCOEF;
    // spline supply: lane og computes packs for bp = og&1
    const float* xp  = x + (size_t)(b0 + wv * 32 + (og & 1) * 16 + bl) * N_IN + i0;
    const float* wgp = W + (size_t)(o0 + (t & 15)) * N_IN + i0 + (t >> 4);

    float4 A0, A1;
    float t0 = 0.f, t1 = 0.f, Wc = 0.f;

#define GLOAD(p) do {                                             \
        const float* _r0 = swrow + (size_t)(2 * (p)) * NCOEF;     \
        const float* _r1 = _r0 + NCOEF;                           \
        A0 = *(const float4*)&_r0[sgc * 4];                       \
        A1 = *(const float4*)&_r1[sgc * 4];                       \
        if (sgc == 63) { t0 = _r0[256]; t1 = _r1[256]; }          \
    } while (0)

#define STAGE(wb) do {                                            \
        unsigned* _s0 = &slab[wb][0][0];                          \
        unsigned* _s1 = &slab[wb][1][0];                          \
        const int _qa = 2 * sgc;                                  \
        _s0[SLOT(_qa,     soo)] = pk_bf16x2(A0.x, A0.y);          \
        _s0[SLOT(_qa + 1, soo)] = pk_bf16x2(A0.z, A0.w);          \
        _s1[SLOT(_qa,     soo)] = pk_bf16x2(A1.x, A1.y);          \
        _s1[SLOT(_qa + 1, soo)] = pk_bf16x2(A1.z, A1.w);          \
        if (sgc == 63) {                                          \
            _s0[SLOT(128, soo)] = pk_bf16x2(t0, 0.f);             \
            _s1[SLOT(128, soo)] = pk_bf16x2(t1, 0.f);             \
        }                                                         \
    } while (0)

    // one bp sub-step: DPP-broadcast pack from quad lane CTRL, FMA + dot2;
    // third q-row skipped when its weight-pair is zero (pbc even, ~50%)
#define DO_BP(bp_, CTRL_, upk_) do {                                          \
        uint4 ub;                                                             \
        ub.x = QP((upk_).x, CTRL_); ub.y = QP((upk_).y, CTRL_);               \
        ub.z = QP((upk_).z, CTRL_); ub.w = QP((upk_).w, CTRL_);               \
        const float tx =                                                      \
            __half2float(__ushort_as_half((unsigned short)(ub.w >> 16)));     \
        float4 a = acc[bp_];                                                  \
        a.x = fmaf(tx, Wv.x, a.x);                                            \
        a.y = fmaf(tx, Wv.y, a.y);                                            \
        a.z = fmaf(tx, Wv.z, a.z);                                            \
        a.w = fmaf(tx, Wv.w, a.w);                                            \
        if (ub.x | ub.y | ub.z) {                                             \
            const int q0 = (int)(ub.w & 0xffffu) >> 1;                        \
            {                                                                 \
                const uint4 s4 =                                              \
                    *(const uint4*)&sl[q0 * ROWQ + ((og ^ (q0 & 3)) << 2)];   \
                a.x = dot2bf(ub.x, s4.x, a.x);                                \
                a.y = dot2bf(ub.x, s4.y, a.y);                                \
                a.z = dot2bf(ub.x, s4.z, a.z);                                \
                a.w = dot2bf(ub.x, s4.w, a.w);                                \
            }                                                                 \
            {                                                                 \
                const int q = q0 + 1;                                         \
                const uint4 s4 =                                              \
                    *(const uint4*)&sl[q * ROWQ + ((og ^ (q & 3)) << 2)];     \
                a.x = dot2bf(ub.y, s4.x, a.x);                                \
                a.y = dot2bf(ub.y, s4.y, a.y);                                \
                a.z = dot2bf(ub.y, s4.z, a.z);                                \
                a.w = dot2bf(ub.y, s4.w, a.w);                                \
            }                                                                 \
            if (ub.z) {                                                       \
                const int q = q0 + 2;                                         \
                const uint4 s4 =                                              \
                    *(const uint4*)&sl[q * ROWQ + ((og ^ (q & 3)) << 2)];     \
                a.x = dot2bf(ub.z, s4.x, a.x);                                \
                a.y = dot2bf(ub.z, s4.y, a.y);                                \
                a.z = dot2bf(ub.z, s4.z, a.z);                                \
                a.w = dot2bf(ub.z, s4.w, a.w);                                \
            }                                                                 \
        }                                                                     \
        acc[bp_] = a;                                                         \
    } while (0)

    float4 acc[2];
    acc[0] = make_float4(0.f, 0.f, 0.f, 0.f);
    acc[1] = make_float4(0.f, 0.f, 0.f, 0.f);

    // ---- prologue: packs+stage pair 0 into buf0; prefetch pair 1
    GLOAD(0);
    const float2 xc = *(const float2*)&xp[0];
    if (t < 32) Wc = wgp[0];
    uint4 pk0 = spline_pack(xc.x);
    uint4 pk1 = spline_pack(xc.y);
    STAGE(0);
    if (t < 32) Wl[0][t >> 4][t & 15] = Wc;
    GLOAD(1);
    float2 xn = *(const float2*)&xp[2];
    if (t < 32) Wc = wgp[2];
    __syncthreads();

    for (int n = 0; n < 16; ++n) {
        const int buf = n & 1;

        // ---- compute pair n; packs for pair n+1 built in the LDS shadows
        {
            const float4 Wv = *(const float4*)&Wl[buf][0][og << 2];
            const unsigned* sl = &slab[buf][0][0];
            DO_BP(0, 0x00, pk0);
            DO_BP(1, 0x55, pk0);
        }
        const uint4 npk0 = spline_pack(xn.x);
        {
            const float4 Wv = *(const float4*)&Wl[buf][1][og << 2];
            const unsigned* sl = &slab[buf][1][0];
            DO_BP(0, 0x00, pk1);
            DO_BP(1, 0x55, pk1);
        }
        const uint4 npk1 = spline_pack(xn.y);

        // ---- stage pair n+1 into the free buffer; prefetch pair n+2
        if (n + 1 < 16) {
            STAGE(buf ^ 1);
            if (t < 32) Wl[buf ^ 1][t >> 4][t & 15] = Wc;
            if (n + 2 < 16) {
                GLOAD(n + 2);
                xn = *(const float2*)&xp[2 * (n + 2)];
                if (t < 32) Wc = wgp[2 * (n + 2)];
            }
        }
        __syncthreads();
        pk0 = npk0;
        pk1 = npk1;
    }

    // ---- write partial slab [ig][b][o]
    float* dst = part + ((size_t)ig * BATCH + b0 + wv * 32 + bl) * N_OUT
               + o0 + (og << 2);
    *reinterpret_cast<float4*>(&dst[0]) = acc[0];
    *reinterpret_cast<float4*>(&dst[(size_t)16 * N_OUT]) = acc[1];
#undef GLOAD
#undef STAGE
#undef DO_BP
}

__global__ __launch_bounds__(256) void kan_ln(
    const float* __restrict__ part, const float* __restrict__ prelu_a,
    float* __restrict__ out)
{
    const int b = blockIdx.x;
    const int t = threadIdx.x;

    float sv = 0.f;
#pragma unroll
    for (int k = 0; k < 16; ++k)
        sv += part[((size_t)k * BATCH + b) * N_OUT + t];

    float v1 = sv, v2 = sv * sv;
#pragma unroll
    for (int d = 1; d < 64; d <<= 1) {
        v1 += __shfl_xor(v1, d);
        v2 += __shfl_xor(v2, d);
    }
    __shared__ float r1[4], r2[4];
    if ((t & 63) == 0) { r1[t >> 6] = v1; r2[t >> 6] = v2; }
    __syncthreads();
    const float tot1 = r1[0] + r1[1] + r1[2] + r1[3];
    const float tot2 = r2[0] + r2[1] + r2[2] + r2[3];

    const float mu  = tot1 * (1.f / N_OUT);
    const float var = tot2 * (1.f / N_OUT) - mu * mu;
    const float inv = rsqrtf(var + LN_EPS);
    const float yn  = (sv - mu) * inv;
    const float a   = prelu_a[0];
    out[(size_t)b * N_OUT + t] = (yn >= 0.f) ? yn : a * yn;
}

extern "C" void kernel_launch(void* const* d_in, const int* in_sizes, int n_in,
                              void* d_out, int out_size, void* d_ws, size_t ws_size,
                              hipStream_t stream)
{
    const float* x  = (const float*)d_in[0];
    const float* W  = (const float*)d_in[1];
    const float* sw = (const float*)d_in[2];
    const float* pa = (const float*)d_in[3];
    float* out  = (float*)d_out;
    float* part = (float*)d_ws;   // 16 * 1024 * 256 floats = 16 MB

    kan_main<<<dim3(512), 1024, 0, stream>>>(x, W, sw, part);
    kan_ln  <<<dim3(1024), 256, 0, stream>>>(part, pa, out);
}

// Round 13
// 101.986 us; speedup vs baseline: 1.1220x; 1.1220x over previous
//
#include <hip/hip_runtime.h>
#include <hip/hip_fp16.h>
#include <math.h>

#define N_IN   512
#define N_OUT  256
#define NCOEF  257
#define BATCH  1024
#define LN_EPS 1e-5f
#define G0F (-1.0f - 3.0f * (2.0f / 254.0f))

#define ROWQ 20                 // dwords per q-row: 16 data + 4 pad
#define NQ   129
#define SLABW (NQ * ROWQ)       // 2580 dwords

// physical dword of logical (q-row, o-col oo in [0,16)): quad-preserving XOR
#define SLOT(q_, oo_) ((q_) * ROWQ + (((((oo_) >> 2) ^ ((q_) & 3))) << 2) + ((oo_) & 3))

static __device__ __forceinline__ unsigned pk_bf16x2(float a, float b) {
    unsigned ua = ((__float_as_uint(a) + 0x8000u) >> 16) & 0xffffu;
    unsigned ub = (__float_as_uint(b) + 0x8000u) & 0xffff0000u;
    return ua | ub;
}

static __device__ __forceinline__ float dot2bf(unsigned w, unsigned s, float c) {
    float d;
    asm("v_dot2_f32_bf16 %0, %1, %2, %3" : "=v"(d) : "v"(w), "v"(s), "v"(c));
    return d;
}

// 6-wide even-aligned spline window: w'[j] for g = pe+j, pe = clamp(pb)&~1.
// uint4: x=(w'0,w'1) y=(w'2,w'3) z=(w'4,w'5) bf16-pairs; w = pe | f16(tanh)<<16
static __device__ __forceinline__ uint4 spline_pack(float xv) {
    const float e2 = __expf(2.f * xv);
    const float tx = 1.f - 2.f / (e2 + 1.f);        // tanh(xv)
    const float u  = (xv - G0F) * 127.f;
    const bool has = (u >= 0.f) && (u < 260.f);
    const float uf = has ? u : 0.f;
    int m = (int)uf;
    if (m > 259) m = 259;
    const float tt = uf - (float)m;
    const float t2 = tt * tt, t3 = t2 * tt;
    const float omt = 1.f - tt;
    float a0 = omt * omt * omt * (1.f / 6.f);
    float a1 = (3.f * t3 - 6.f * t2 + 4.f) * (1.f / 6.f);
    float a2 = (-3.f * t3 + 3.f * t2 + 3.f * tt + 1.f) * (1.f / 6.f);
    float a3 = t3 * (1.f / 6.f);
    if (!has) { a0 = a1 = a2 = a3 = 0.f; }
    const int pb  = m - 3;
    const int pbc = pb < 0 ? 0 : (pb > 253 ? 253 : pb);
    const int d   = pbc - pb;                       // [-3,3]
    if (d >= 1)  { a0 = a1; a1 = a2; a2 = a3; a3 = 0.f; }
    if (d >= 2)  { a0 = a1; a1 = a2; a2 = a3; a3 = 0.f; }
    if (d >= 3)  { a0 = a1; a1 = a2; a2 = a3; a3 = 0.f; }
    if (d <= -1) { a3 = a2; a2 = a1; a1 = a0; a0 = 0.f; }
    if (d <= -2) { a3 = a2; a2 = a1; a1 = a0; a0 = 0.f; }
    if (d <= -3) { a3 = a2; a2 = a1; a1 = a0; a0 = 0.f; }
    uint4 r;
    if (pbc & 1) {        // window (0,a0,a1,a2,a3,0)
        r.x = pk_bf16x2(0.f, a0);
        r.y = pk_bf16x2(a1, a2);
        r.z = pk_bf16x2(a3, 0.f);
    } else {              // window (a0,a1,a2,a3,0,0)
        r.x = pk_bf16x2(a0, a1);
        r.y = pk_bf16x2(a2, a3);
        r.z = 0u;
    }
    r.w = (unsigned)(pbc & ~1) |
          ((unsigned)__half_as_ushort(__float2half(tx)) << 16);
    return r;
}

__global__ __launch_bounds__(512, 4) void kan_main(
    const float* __restrict__ x, const float* __restrict__ W,
    const float* __restrict__ sw, float* __restrict__ part)
{
    const int bid = blockIdx.x;
    const int bc = bid & 1;             // fastest: the 2 slab-sharers co-resident
    const int oc = (bid >> 1) & 15;
    const int ig = bid >> 5;            // [0,16)
    const int o0 = oc * 16, i0 = ig * 32, b0 = bc * 512;
    const int t = threadIdx.x;

    __shared__ __align__(16) unsigned slab[2][2][SLABW]; // 41.3 KB (dbuf x 2 sub)
    __shared__ __align__(16) uint4 wpk[2][512];          // 16 KB (wave-private)
    __shared__ float Wl[2][2][16];

    // compute mapping: wave wv owns local b in [wv*64, wv*64+64)
    const int wv = t >> 6;                 // [0,8)
    const int bl = (t >> 2) & 15, og = t & 3;
    // staging mapping: o-row soo (fast), float4-chunk sgc
    const int soo = t & 15;                // [0,16)
    const int sgc = t >> 4;                // [0,32)

    const float* swrow = sw + ((size_t)(o0 + soo) * N_IN + i0) * NCOEF;
    const float* xp    = x + (size_t)(b0 + t) * N_IN + i0;   // own local b = t
    const float* wgp   = W + (size_t)(o0 + (t & 15)) * N_IN + i0 + (t >> 4);

    float4 A0, B0, A1, B1;
    float t0 = 0.f, t1 = 0.f, Wc = 0.f;

#define GLOAD(p) do {                                             \
        const float* _r0 = swrow + (size_t)(2 * (p)) * NCOEF;     \
        const float* _r1 = _r0 + NCOEF;                           \
        A0 = *(const float4*)&_r0[sgc * 4];                       \
        B0 = *(const float4*)&_r0[sgc * 4 + 128];                 \
        A1 = *(const float4*)&_r1[sgc * 4];                       \
        B1 = *(const float4*)&_r1[sgc * 4 + 128];                 \
        if (sgc == 31) { t0 = _r0[256]; t1 = _r1[256]; }          \
    } while (0)

#define STAGE(wb) do {                                            \
        unsigned* _s0 = &slab[wb][0][0];                          \
        unsigned* _s1 = &slab[wb][1][0];                          \
        const int _qa = 2 * sgc;                                  \
        _s0[SLOT(_qa,      soo)] = pk_bf16x2(A0.x, A0.y);         \
        _s0[SLOT(_qa + 1,  soo)] = pk_bf16x2(A0.z, A0.w);         \
        _s0[SLOT(_qa + 64, soo)] = pk_bf16x2(B0.x, B0.y);         \
        _s0[SLOT(_qa + 65, soo)] = pk_bf16x2(B0.z, B0.w);         \
        _s1[SLOT(_qa,      soo)] = pk_bf16x2(A1.x, A1.y);         \
        _s1[SLOT(_qa + 1,  soo)] = pk_bf16x2(A1.z, A1.w);         \
        _s1[SLOT(_qa + 64, soo)] = pk_bf16x2(B1.x, B1.y);         \
        _s1[SLOT(_qa + 65, soo)] = pk_bf16x2(B1.z, B1.w);         \
        if (sgc == 31) {                                          \
            _s0[SLOT(128, soo)] = pk_bf16x2(t0, 0.f);             \
            _s1[SLOT(128, soo)] = pk_bf16x2(t1, 0.f);             \
        }                                                         \
    } while (0)

    float4 acc[4];
#pragma unroll
    for (int bp = 0; bp < 4; ++bp) acc[bp] = make_float4(0.f, 0.f, 0.f, 0.f);

    // ---- prologue: stage pair 0 into buf0 (slab + wpk + Wl); prefetch pair 1
    GLOAD(0);
    float2 xc = *(const float2*)&xp[0];
    if (t < 32) Wc = wgp[0];
    STAGE(0);
    if (t < 32) Wl[0][t >> 4][t & 15] = Wc;
    wpk[0][t] = spline_pack(xc.x);
    wpk[1][t] = spline_pack(xc.y);
    GLOAD(1);
    float2 xn = *(const float2*)&xp[2];
    if (t < 32) Wc = wgp[2];
    __syncthreads();

    for (int n = 0; n < 16; ++n) {
        const int buf = n & 1;

        // ---- compute pair n from slab[buf] / wpk / Wl[buf]
#pragma unroll
        for (int sub = 0; sub < 2; ++sub) {
            const float4 Wv = *(const float4*)&Wl[buf][sub][og << 2];
            const unsigned* sl = &slab[buf][sub][0];
#pragma unroll
            for (int bp = 0; bp < 4; ++bp) {
                const uint4 u = wpk[sub][wv * 64 + (bp << 4) + bl]; // broadcast
                const float tx =
                    __half2float(__ushort_as_half((unsigned short)(u.w >> 16)));
                float4 a = acc[bp];
                a.x = fmaf(tx, Wv.x, a.x);
                a.y = fmaf(tx, Wv.y, a.y);
                a.z = fmaf(tx, Wv.z, a.z);
                a.w = fmaf(tx, Wv.w, a.w);
                if (u.x | u.y | u.z) {      // ~69% of lanes have support
                    const int q0 = (int)(u.w & 0xffffu) >> 1;
                    {
                        const uint4 s4 =
                            *(const uint4*)&sl[q0 * ROWQ + ((og ^ (q0 & 3)) << 2)];
                        a.x = dot2bf(u.x, s4.x, a.x);
                        a.y = dot2bf(u.x, s4.y, a.y);
                        a.z = dot2bf(u.x, s4.z, a.z);
                        a.w = dot2bf(u.x, s4.w, a.w);
                    }
                    {
                        const int q = q0 + 1;
                        const uint4 s4 =
                            *(const uint4*)&sl[q * ROWQ + ((og ^ (q & 3)) << 2)];
                        a.x = dot2bf(u.y, s4.x, a.x);
                        a.y = dot2bf(u.y, s4.y, a.y);
                        a.z = dot2bf(u.y, s4.z, a.z);
                        a.w = dot2bf(u.y, s4.w, a.w);
                    }
                    if (u.z) {              // third pair zero when pbc even
                        const int q = q0 + 2;
                        const uint4 s4 =
                            *(const uint4*)&sl[q * ROWQ + ((og ^ (q & 3)) << 2)];
                        a.x = dot2bf(u.z, s4.x, a.x);
                        a.y = dot2bf(u.z, s4.y, a.y);
                        a.z = dot2bf(u.z, s4.z, a.z);
                        a.w = dot2bf(u.z, s4.w, a.w);
                    }
                }
                acc[bp] = a;
            }
        }

        // ---- stage pair n+1 into free buffer; wpk is wave-private (own reads
        // done above in program order); prefetch pair n+2
        if (n + 1 < 16) {
            STAGE(buf ^ 1);
            if (t < 32) Wl[buf ^ 1][t >> 4][t & 15] = Wc;
            wpk[0][t] = spline_pack(xn.x);
            wpk[1][t] = spline_pack(xn.y);
            if (n + 2 < 16) {
                GLOAD(n + 2);
                xn = *(const float2*)&xp[2 * (n + 2)];
                if (t < 32) Wc = wgp[2 * (n + 2)];
            }
        }
        __syncthreads();
    }

    // ---- write partial slab [ig][b][o]
    float* dst = part + ((size_t)ig * BATCH + b0) * N_OUT + o0 + (og << 2);
#pragma unroll
    for (int bp = 0; bp < 4; ++bp) {
        const int lb = wv * 64 + (bp << 4) + bl;
        *reinterpret_cast<float4*>(&dst[(size_t)lb * N_OUT]) = acc[bp];
    }
#undef GLOAD
#undef STAGE
}

__global__ __launch_bounds__(256) void kan_ln(
    const float* __restrict__ part, const float* __restrict__ prelu_a,
    float* __restrict__ out)
{
    const int b = blockIdx.x;
    const int t = threadIdx.x;

    float sv = 0.f;
#pragma unroll
    for (int k = 0; k < 16; ++k)
        sv += part[((size_t)k * BATCH + b) * N_OUT + t];

    float v1 = sv, v2 = sv * sv;
#pragma unroll
    for (int d = 1; d < 64; d <<= 1) {
        v1 += __shfl_xor(v1, d);
        v2 += __shfl_xor(v2, d);
    }
    __shared__ float r1[4], r2[4];
    if ((t & 63) == 0) { r1[t >> 6] = v1; r2[t >> 6] = v2; }
    __syncthreads();
    const float tot1 = r1[0] + r1[1] + r1[2] + r1[3];
    const float tot2 = r2[0] + r2[1] + r2[2] + r2[3];

    const float mu  = tot1 * (1.f / N_OUT);
    const float var = tot2 * (1.f / N_OUT) - mu * mu;
    const float inv = rsqrtf(var + LN_EPS);
    const float yn  = (sv - mu) * inv;
    const float a   = prelu_a[0];
    out[(size_t)b * N_OUT + t] = (yn >= 0.f) ? yn : a * yn;
}

extern "C" void kernel_launch(void* const* d_in, const int* in_sizes, int n_in,
                              void* d_out, int out_size, void* d_ws, size_t ws_size,
                              hipStream_t stream)
{
    const float* x  = (const float*)d_in[0];
    const float* W  = (const float*)d_in[1];
    const float* sw = (const float*)d_in[2];
    const float* pa = (const float*)d_in[3];
    float* out  = (float*)d_out;
    float* part = (float*)d_ws;   // 16 * 1024 * 256 floats = 16 MB

    kan_main<<<dim3(512), 512, 0, stream>>>(x, W, sw, part);
    kan_ln  <<<dim3(1024), 256, 0, stream>>>(part, pa, out);
}

// Round 14
// 94.735 us; speedup vs baseline: 1.2079x; 1.0765x over previous
//
#include <hip/hip_runtime.h>
#include <hip/hip_fp16.h>
#include <math.h>

#define N_IN   512
#define N_OUT  256
#define NCOEF  257
#define BATCH  1024
#define LN_EPS 1e-5f
#define G0F (-1.0f - 3.0f * (2.0f / 254.0f))

#define ROWQ 20                 // dwords per q-row: 16 data + 4 pad
#define NQ   129
#define SLABW (NQ * ROWQ)       // 2580 dwords

// physical dword of logical (q-row, o-col oo in [0,16)): quad-preserving XOR
#define SLOT(q_, oo_) ((q_) * ROWQ + (((((oo_) >> 2) ^ ((q_) & 3))) << 2) + ((oo_) & 3))

// DPP quad_perm broadcast: all 4 lanes of a quad read the ctrl-selected lane
#define QP(v_, C_) ((unsigned)__builtin_amdgcn_mov_dpp((int)(v_), (C_), 0xf, 0xf, true))

static __device__ __forceinline__ unsigned pk_bf16x2(float a, float b) {
    unsigned ua = ((__float_as_uint(a) + 0x8000u) >> 16) & 0xffffu;
    unsigned ub = (__float_as_uint(b) + 0x8000u) & 0xffff0000u;
    return ua | ub;
}

static __device__ __forceinline__ float dot2bf(unsigned w, unsigned s, float c) {
    float d;
    asm("v_dot2_f32_bf16 %0, %1, %2, %3" : "=v"(d) : "v"(w), "v"(s), "v"(c));
    return d;
}

// 6-wide even-aligned spline window: w'[j] for g = pe+j, pe = clamp(pb)&~1.
// uint4: x=(w'0,w'1) y=(w'2,w'3) z=(w'4,w'5) bf16-pairs; w = pe | f16(tanh)<<16
static __device__ __forceinline__ uint4 spline_pack(float xv) {
    const float e2 = __expf(2.f * xv);
    const float tx = 1.f - 2.f / (e2 + 1.f);        // tanh(xv)
    const float u  = (xv - G0F) * 127.f;
    const bool has = (u >= 0.f) && (u < 260.f);
    const float uf = has ? u : 0.f;
    int m = (int)uf;
    if (m > 259) m = 259;
    const float tt = uf - (float)m;
    const float t2 = tt * tt, t3 = t2 * tt;
    const float omt = 1.f - tt;
    float a0 = omt * omt * omt * (1.f / 6.f);
    float a1 = (3.f * t3 - 6.f * t2 + 4.f) * (1.f / 6.f);
    float a2 = (-3.f * t3 + 3.f * t2 + 3.f * tt + 1.f) * (1.f / 6.f);
    float a3 = t3 * (1.f / 6.f);
    if (!has) { a0 = a1 = a2 = a3 = 0.f; }
    const int pb  = m - 3;
    const int pbc = pb < 0 ? 0 : (pb > 253 ? 253 : pb);
    const int d   = pbc - pb;                       // [-3,3]
    if (d >= 1)  { a0 = a1; a1 = a2; a2 = a3; a3 = 0.f; }
    if (d >= 2)  { a0 = a1; a1 = a2; a2 = a3; a3 = 0.f; }
    if (d >= 3)  { a0 = a1; a1 = a2; a2 = a3; a3 = 0.f; }
    if (d <= -1) { a3 = a2; a2 = a1; a1 = a0; a0 = 0.f; }
    if (d <= -2) { a3 = a2; a2 = a1; a1 = a0; a0 = 0.f; }
    if (d <= -3) { a3 = a2; a2 = a1; a1 = a0; a0 = 0.f; }
    uint4 r;
    if (pbc & 1) {        // window (0,a0,a1,a2,a3,0)
        r.x = pk_bf16x2(0.f, a0);
        r.y = pk_bf16x2(a1, a2);
        r.z = pk_bf16x2(a3, 0.f);
    } else {              // window (a0,a1,a2,a3,0,0)
        r.x = pk_bf16x2(a0, a1);
        r.y = pk_bf16x2(a2, a3);
        r.z = 0u;
    }
    r.w = (unsigned)(pbc & ~1) |
          ((unsigned)__half_as_ushort(__float2half(tx)) << 16);
    return r;
}

__global__ __launch_bounds__(1024, 4) void kan_main(
    const float* __restrict__ x, const float* __restrict__ W,
    const float* __restrict__ sw, float* __restrict__ part)
{
    const int bid = blockIdx.x;
    const int oc = bid & 15;
    const int ig = bid >> 4;            // [0,16)
    const int o0 = oc * 16, i0 = ig * 32;
    const int t = threadIdx.x;

    __shared__ __align__(16) unsigned slab[2][2][SLABW]; // 41.3 KB (dbuf x 2 sub)
    __shared__ float Wl[2][2][16];

    // compute mapping: wave wv owns b in [wv*64, wv*64+64); quad=(bl), lane og
    const int wv = t >> 6;                 // [0,16)
    const int bl = (t >> 2) & 15, og = t & 3;
    // staging mapping: o-row soo (fast), float4-chunk sgc
    const int soo = t & 15;                // [0,16)
    const int sgc = t >> 4;                // [0,64)

    const float* swrow = sw + ((size_t)(o0 + soo) * N_IN + i0) * NCOEF;
    // spline supply: this lane computes packs for b_supply (quad holds 4 bp's)
    const float* xp  = x + (size_t)(wv * 64 + og * 16 + bl) * N_IN + i0;
    const float* wgp = W + (size_t)(o0 + (t & 15)) * N_IN + i0 + (t >> 4);

    float4 pf0, pf1;
    float t0 = 0.f, t1 = 0.f, Wc = 0.f;

#define GLOAD(p) do {                                             \
        const float* _r0 = swrow + (size_t)(2 * (p)) * NCOEF;     \
        const float* _r1 = _r0 + NCOEF;                           \
        pf0 = *(const float4*)&_r0[sgc * 4];                      \
        pf1 = *(const float4*)&_r1[sgc * 4];                      \
        if (sgc == 63) { t0 = _r0[256]; t1 = _r1[256]; }          \
    } while (0)

#define STAGE(wb) do {                                            \
        unsigned* _s0 = &slab[wb][0][0];                          \
        unsigned* _s1 = &slab[wb][1][0];                          \
        const int _qa = 2 * sgc;                                  \
        _s0[SLOT(_qa,     soo)] = pk_bf16x2(pf0.x, pf0.y);        \
        _s0[SLOT(_qa + 1, soo)] = pk_bf16x2(pf0.z, pf0.w);        \
        _s1[SLOT(_qa,     soo)] = pk_bf16x2(pf1.x, pf1.y);        \
        _s1[SLOT(_qa + 1, soo)] = pk_bf16x2(pf1.z, pf1.w);        \
        if (sgc == 63) {                                          \
            _s0[SLOT(128, soo)] = pk_bf16x2(t0, 0.f);             \
            _s1[SLOT(128, soo)] = pk_bf16x2(t1, 0.f);             \
        }                                                         \
    } while (0)

    // one bp sub-step: DPP quad-broadcast pack from lane og=bp, FMA + dot2;
    // third q-row skipped when its weight-pair is zero (pbc even, ~50%)
#define DO_BP(bp_, CTRL_, upk_) do {                                          \
        uint4 ub;                                                             \
        ub.x = QP((upk_).x, CTRL_); ub.y = QP((upk_).y, CTRL_);               \
        ub.z = QP((upk_).z, CTRL_); ub.w = QP((upk_).w, CTRL_);               \
        const float tx =                                                      \
            __half2float(__ushort_as_half((unsigned short)(ub.w >> 16)));     \
        float4 a = acc[bp_];                                                  \
        a.x = fmaf(tx, Wv.x, a.x);                                            \
        a.y = fmaf(tx, Wv.y, a.y);                                            \
        a.z = fmaf(tx, Wv.z, a.z);                                            \
        a.w = fmaf(tx, Wv.w, a.w);                                            \
        if (ub.x | ub.y | ub.z) {                                             \
            const int q0 = (int)(ub.w & 0xffffu) >> 1;                        \
            {                                                                 \
                const uint4 s4 =                                              \
                    *(const uint4*)&sl[q0 * ROWQ + ((og ^ (q0 & 3)) << 2)];   \
                a.x = dot2bf(ub.x, s4.x, a.x);                                \
                a.y = dot2bf(ub.x, s4.y, a.y);                                \
                a.z = dot2bf(ub.x, s4.z, a.z);                                \
                a.w = dot2bf(ub.x, s4.w, a.w);                                \
            }                                                                 \
            {                                                                 \
                const int q = q0 + 1;                                         \
                const uint4 s4 =                                              \
                    *(const uint4*)&sl[q * ROWQ + ((og ^ (q & 3)) << 2)];     \
                a.x = dot2bf(ub.y, s4.x, a.x);                                \
                a.y = dot2bf(ub.y, s4.y, a.y);                                \
                a.z = dot2bf(ub.y, s4.z, a.z);                                \
                a.w = dot2bf(ub.y, s4.w, a.w);                                \
            }                                                                 \
            if (ub.z) {                                                       \
                const int q = q0 + 2;                                         \
                const uint4 s4 =                                              \
                    *(const uint4*)&sl[q * ROWQ + ((og ^ (q & 3)) << 2)];     \
                a.x = dot2bf(ub.z, s4.x, a.x);                                \
                a.y = dot2bf(ub.z, s4.y, a.y);                                \
                a.z = dot2bf(ub.z, s4.z, a.z);                                \
                a.w = dot2bf(ub.z, s4.w, a.w);                                \
            }                                                                 \
        }                                                                     \
        acc[bp_] = a;                                                         \
    } while (0)

    float4 acc[4];
#pragma unroll
    for (int bp = 0; bp < 4; ++bp) acc[bp] = make_float4(0.f, 0.f, 0.f, 0.f);

    // ---- prologue: packs + stage pair 0 into buf0; prefetch pair 1
    GLOAD(0);
    float2 xc = *(const float2*)&xp[0];
    if (t < 32) Wc = wgp[0];
    uint4 pk0 = spline_pack(xc.x);
    uint4 pk1 = spline_pack(xc.y);
    STAGE(0);
    if (t < 32) Wl[0][t >> 4][t & 15] = Wc;
    GLOAD(1);
    float2 xn = *(const float2*)&xp[2];
    if (t < 32) Wc = wgp[2];
    __syncthreads();

    for (int n = 0; n < 16; ++n) {
        const int buf = n & 1;

        // ---- compute pair n; next-pair packs built in the LDS shadows
        {
            const float4 Wv = *(const float4*)&Wl[buf][0][og << 2];
            const unsigned* sl = &slab[buf][0][0];
            DO_BP(0, 0x00, pk0);
            DO_BP(1, 0x55, pk0);
            DO_BP(2, 0xAA, pk0);
            DO_BP(3, 0xFF, pk0);
        }
        const uint4 npk0 = spline_pack(xn.x);
        {
            const float4 Wv = *(const float4*)&Wl[buf][1][og << 2];
            const unsigned* sl = &slab[buf][1][0];
            DO_BP(0, 0x00, pk1);
            DO_BP(1, 0x55, pk1);
            DO_BP(2, 0xAA, pk1);
            DO_BP(3, 0xFF, pk1);
        }
        const uint4 npk1 = spline_pack(xn.y);

        // ---- stage pair n+1 into the free buffer; prefetch pair n+2
        if (n + 1 < 16) {
            STAGE(buf ^ 1);
            if (t < 32) Wl[buf ^ 1][t >> 4][t & 15] = Wc;
            if (n + 2 < 16) {
                GLOAD(n + 2);
                xn = *(const float2*)&xp[2 * (n + 2)];
                if (t < 32) Wc = wgp[2 * (n + 2)];
            }
        }
        __syncthreads();
        pk0 = npk0;
        pk1 = npk1;
    }

    // ---- write partial slab [ig][b][o]
    float* dst = part + ((size_t)ig * BATCH) * N_OUT + o0 + (og << 2);
#pragma unroll
    for (int bp = 0; bp < 4; ++bp) {
        const int lb = wv * 64 + (bp << 4) + bl;
        *reinterpret_cast<float4*>(&dst[(size_t)lb * N_OUT]) = acc[bp];
    }
#undef GLOAD
#undef STAGE
#undef DO_BP
}

__global__ __launch_bounds__(256) void kan_ln(
    const float* __restrict__ part, const float* __restrict__ prelu_a,
    float* __restrict__ out)
{
    const int b = blockIdx.x;
    const int t = threadIdx.x;

    float sv = 0.f;
#pragma unroll
    for (int k = 0; k < 16; ++k)
        sv += part[((size_t)k * BATCH + b) * N_OUT + t];

    float v1 = sv, v2 = sv * sv;
#pragma unroll
    for (int d = 1; d < 64; d <<= 1) {
        v1 += __shfl_xor(v1, d);
        v2 += __shfl_xor(v2, d);
    }
    __shared__ float r1[4], r2[4];
    if ((t & 63) == 0) { r1[t >> 6] = v1; r2[t >> 6] = v2; }
    __syncthreads();
    const float tot1 = r1[0] + r1[1] + r1[2] + r1[3];
    const float tot2 = r2[0] + r2[1] + r2[2] + r2[3];

    const float mu  = tot1 * (1.f / N_OUT);
    const float var = tot2 * (1.f / N_OUT) - mu * mu;
    const float inv = rsqrtf(var + LN_EPS);
    const float yn  = (sv - mu) * inv;
    const float a   = prelu_a[0];
    out[(size_t)b * N_OUT + t] = (yn >= 0.f) ? yn : a * yn;
}

extern "C" void kernel_launch(void* const* d_in, const int* in_sizes, int n_in,
                              void* d_out, int out_size, void* d_ws, size_t ws_size,
                              hipStream_t stream)
{
    const float* x  = (const float*)d_in[0];
    const float* W  = (const float*)d_in[1];
    const float* sw = (const float*)d_in[2];
    const float* pa = (const float*)d_in[3];
    float* out  = (float*)d_out;
    float* part = (float*)d_ws;   // 16 * 1024 * 256 floats = 16 MB

    kan_main<<<dim3(256), 1024, 0, stream>>>(x, W, sw, part);
    kan_ln  <<<dim3(1024), 256, 0, stream>>>(part, pa, out);
}